// Round 1
// baseline (945.879 us; speedup 1.0000x reference)
//
// DNCCell MI355X implementation — round 1 (correctness-first, fused per-b kernels)
//
// Structure (13 kernel launches):
//   k_init_read            : mem = inputs+state (bf16, global+LDS), read-score(0), softmax, att(0)
//   per layer l=0..3:
//     k_gemm<true>         : x1 = relu(att @ kernW[l] + kernb[l])      (bf16 MFMA 16x16x32)
//     k_gemm<false>        : x2 = x1 @ projW[l] + projb[l]
//     k_write_read<L==3>   : LN(x2) -> write-score/softmax -> mem update (in LDS) ->
//                            next read-score/softmax -> att  (last layer: r1+r2 reads -> d_out)
//
// mem is carried as bf16 (33.5MB global, 131KB LDS per block). All score math fp32.

#include <hip/hip_runtime.h>
#include <cstdint>
#include <cstddef>

#define BB 256
#define MM 64
#define UDIM 1024
#define HN 16
#define POSN 32
#define PROJ 1056
#define MEMSTRIDE 1026   // bf16 elems per LDS mem row: odd word stride -> conflict-free m-scans

using f32x4 = __attribute__((ext_vector_type(4))) float;
using s16x8 = __attribute__((ext_vector_type(8))) short;

__device__ unsigned short g_mem[BB * MM * UDIM];   // bf16 bits
__device__ float g_att[BB * UDIM];
__device__ float g_x1[BB * UDIM];
__device__ float g_x2[BB * PROJ];

__device__ __forceinline__ float bf2f(unsigned short u) {
    unsigned int x = ((unsigned int)u) << 16; float f; __builtin_memcpy(&f, &x, 4); return f;
}
__device__ __forceinline__ unsigned short f2bf(float f) {
    unsigned int x; __builtin_memcpy(&x, &f, 4);
    x += 0x7fffu + ((x >> 16) & 1u);           // round-to-nearest-even
    return (unsigned short)(x >> 16);
}
__device__ __forceinline__ unsigned int packbf(float a, float b) {
    return (unsigned int)f2bf(a) | ((unsigned int)f2bf(b) << 16);
}
__device__ __forceinline__ float wsum(float v) {
#pragma unroll
    for (int o = 32; o; o >>= 1) v += __shfl_xor(v, o);
    return v;
}
__device__ __forceinline__ float wmax(float v) {
#pragma unroll
    for (int o = 32; o; o >>= 1) v = fmaxf(v, __shfl_xor(v, o));
    return v;
}
// acc[0..15] += val * wrow[0..15]  (wrow is wave-uniform -> scalar loads)
__device__ __forceinline__ void fma16(float* acc, float val, const float* __restrict__ wrow) {
    float4 a = *(const float4*)(wrow);
    float4 b = *(const float4*)(wrow + 4);
    float4 c = *(const float4*)(wrow + 8);
    float4 d = *(const float4*)(wrow + 12);
    acc[0]  += val * a.x; acc[1]  += val * a.y; acc[2]  += val * a.z; acc[3]  += val * a.w;
    acc[4]  += val * b.x; acc[5]  += val * b.y; acc[6]  += val * b.z; acc[7]  += val * b.w;
    acc[8]  += val * c.x; acc[9]  += val * c.y; acc[10] += val * c.z; acc[11] += val * c.w;
    acc[12] += val * d.x; acc[13] += val * d.y; acc[14] += val * d.z; acc[15] += val * d.w;
}

// Finish one score set: atomic-reduce partials, add mean-term (+x-term), pos-term, bias,
// softmax over m per h. Caller must have zeroed s_score and synced before calling.
// Layout: wave w handles column h=w; lane l handles row m=l. Row stride 17 (bank spread).
template<bool WITHX>
__device__ __forceinline__ void score_phase(
    float* s_score, float* s_out, float* s_c,
    const float* acc, const float* __restrict__ Wm, const float* __restrict__ bv,
    const float* __restrict__ pe, const float* s_x, int w, int l)
{
#pragma unroll
    for (int h = 0; h < HN; ++h) atomicAdd(&s_score[l * 17 + h], acc[h]);
    __syncthreads();
    {
        const int h = w;
        float xpart = 0.f;
        if (WITHX) {
#pragma unroll 4
            for (int k = 0; k < 17; ++k) {
                int p = l + (k << 6);
                if (p < PROJ) xpart += s_x[p] * Wm[p * HN + h];
            }
        }
        float msum = wsum(s_score[l * 17 + h]);   // Sum_m score0 -> mean-key term
        if (WITHX) xpart = wsum(xpart);
        if (l == 0) s_c[h] = msum * (1.0f / 64.0f) + xpart + bv[h];
    }
    __syncthreads();
    {
        const int h = w;
        float posr = 0.f;
        const float* per = pe + l * POSN;
#pragma unroll
        for (int p = 0; p < POSN; ++p) posr += per[p] * Wm[(UDIM + p) * HN + h];
        float sc = s_score[l * 17 + h] + s_c[h] + posr;
        float mx = wmax(sc);
        float e = __expf(sc - mx);
        float sm = wsum(e);
        s_out[l * 17 + h] = e / sm;
    }
    __syncthreads();
}

__global__ __launch_bounds__(1024) void k_init_read(
    const float* __restrict__ inp, const float* __restrict__ st,
    const float* __restrict__ rW, const float* __restrict__ rb,
    const float* __restrict__ pe)
{
    __shared__ unsigned short s_mem[MM * MEMSTRIDE];
    __shared__ float s_score[MM * 17];
    __shared__ float s_wts[MM * 17];
    __shared__ float s_c[HN];
    const int t = threadIdx.x, b = blockIdx.x, w = t >> 6, l = t & 63;
    s_score[(t >> 4) * 17 + (t & 15)] = 0.f;

    const float* ip = inp + (size_t)b * (MM * UDIM);
    const float* sp = st + (size_t)b * (MM * UDIM);
    unsigned short* gm = g_mem + (size_t)b * (MM * UDIM);
#pragma unroll 2
    for (int k = 0; k < 16; ++k) {
        int flat = (k * 1024 + t) * 4;
        float4 a = *(const float4*)(ip + flat);
        float4 c = *(const float4*)(sp + flat);
        unsigned int p0 = packbf(a.x + c.x, a.y + c.y);
        unsigned int p1 = packbf(a.z + c.z, a.w + c.w);
        unsigned int* dst = (unsigned int*)&s_mem[(flat >> 10) * MEMSTRIDE + (flat & 1023)];
        dst[0] = p0; dst[1] = p1;
        uint2 vv; vv.x = p0; vv.y = p1;
        *(uint2*)(gm + flat) = vv;
    }
    __syncthreads();

    // read-score(0): lane l = slot m, wave w = u-span [64w, 64w+64)
    float acc[HN];
#pragma unroll
    for (int h = 0; h < HN; ++h) acc[h] = 0.f;
    {
        const int ub = w << 6;
#pragma unroll 2
        for (int j = 0; j < 64; ++j) {
            int u = ub + j;
            float val = bf2f(s_mem[l * MEMSTRIDE + u]);
            fma16(acc, val, rW + (size_t)HN * __builtin_amdgcn_readfirstlane(u));
        }
    }
    score_phase<false>(s_score, s_wts, s_c, acc, rW, rb, pe, nullptr, w, l);

    // att(0): thread t = output u; h = u>>6 (wave-uniform)
    {
        const int u = t, h = t >> 6;
        float a = 0.f;
#pragma unroll 4
        for (int m = 0; m < MM; ++m) a += s_wts[m * 17 + h] * bf2f(s_mem[m * MEMSTRIDE + u]);
        g_att[(size_t)b * UDIM + u] = a;
    }
}

// C[256 x N] = op(A[256 x 1024] @ W[1024 x N] + bias). bf16 MFMA, fp32 staging->cvt.
template<bool RELU>
__global__ __launch_bounds__(256) void k_gemm(
    const float* __restrict__ W, const float* __restrict__ bias, int N)
{
    const float* A = RELU ? (const float*)g_att : (const float*)g_x1;
    float* C = RELU ? (float*)g_x1 : (float*)g_x2;
    __shared__ unsigned short s_a[64 * 40];   // [64 rows][32 k] bf16, stride 40 (16B-aligned rows)
    __shared__ unsigned short s_w[32 * 40];   // [32 n][32 k] bf16 (W transposed)
    const int t = threadIdx.x, w = t >> 6, l = t & 63;
    const int col0 = blockIdx.x * 32, row0 = blockIdx.y * 64;
    f32x4 acc0 = {0.f, 0.f, 0.f, 0.f}, acc1 = {0.f, 0.f, 0.f, 0.f};
    const int ar = t >> 2, kq = (t & 3) << 3;  // A stage: 4 thr/row x 8 k
    const int kk = t >> 3, n4 = (t & 7) << 2;  // W stage: 8 thr/k-row x 4 n
    for (int k0 = 0; k0 < 1024; k0 += 32) {
        float4 a0 = *(const float4*)(A + (size_t)(row0 + ar) * 1024 + k0 + kq);
        float4 a1 = *(const float4*)(A + (size_t)(row0 + ar) * 1024 + k0 + kq + 4);
        float4 wv = *(const float4*)(W + (size_t)(k0 + kk) * N + col0 + n4);
        unsigned int* dst = (unsigned int*)&s_a[ar * 40 + kq];
        dst[0] = packbf(a0.x, a0.y); dst[1] = packbf(a0.z, a0.w);
        dst[2] = packbf(a1.x, a1.y); dst[3] = packbf(a1.z, a1.w);
        s_w[(n4 + 0) * 40 + kk] = f2bf(wv.x);
        s_w[(n4 + 1) * 40 + kk] = f2bf(wv.y);
        s_w[(n4 + 2) * 40 + kk] = f2bf(wv.z);
        s_w[(n4 + 3) * 40 + kk] = f2bf(wv.w);
        __syncthreads();
        const int fr = (w << 4) + (l & 15), k8 = (l >> 4) << 3;
        s16x8 af = *(const s16x8*)&s_a[fr * 40 + k8];
        s16x8 b0 = *(const s16x8*)&s_w[(l & 15) * 40 + k8];
        s16x8 b1 = *(const s16x8*)&s_w[((l & 15) + 16) * 40 + k8];
        acc0 = __builtin_amdgcn_mfma_f32_16x16x32_bf16(af, b0, acc0, 0, 0, 0);
        acc1 = __builtin_amdgcn_mfma_f32_16x16x32_bf16(af, b1, acc1, 0, 0, 0);
        __syncthreads();
    }
    const int ca = col0 + (l & 15), cb = ca + 16;
    const int r0 = row0 + (w << 4) + ((l >> 4) << 2);
    float ba = bias[ca], bbv = bias[cb];
#pragma unroll
    for (int j = 0; j < 4; ++j) {
        float v0 = acc0[j] + ba, v1 = acc1[j] + bbv;
        if (RELU) { v0 = fmaxf(v0, 0.f); v1 = fmaxf(v1, 0.f); }
        C[(size_t)(r0 + j) * N + ca] = v0;
        C[(size_t)(r0 + j) * N + cb] = v1;
    }
}

template<bool LAST>
__global__ __launch_bounds__(1024) void k_write_read(
    const float* __restrict__ lnG, const float* __restrict__ lnB,
    const float* __restrict__ wW, const float* __restrict__ wb,
    const float* __restrict__ rW1, const float* __restrict__ rb1,
    const float* __restrict__ rW2, const float* __restrict__ rb2,
    const float* __restrict__ pe,
    float* __restrict__ out_final, float* __restrict__ memout)
{
    __shared__ unsigned short s_mem[MM * MEMSTRIDE];
    __shared__ float s_x[PROJ];
    __shared__ float s_score[MM * 17];
    __shared__ float s_w1[MM * 17];
    __shared__ float s_w2[MM * 17];
    __shared__ float s_c[HN];
    __shared__ float s_red[34];
    const int t = threadIdx.x, b = blockIdx.x, w = t >> 6, l = t & 63;
    unsigned short* gm = g_mem + (size_t)b * (MM * UDIM);
    s_score[(t >> 4) * 17 + (t & 15)] = 0.f;

#pragma unroll 2
    for (int k = 0; k < 16; ++k) {
        int flat = (k * 1024 + t) * 4;
        uint2 v = *(const uint2*)(gm + flat);
        unsigned int* dst = (unsigned int*)&s_mem[(flat >> 10) * MEMSTRIDE + (flat & 1023)];
        dst[0] = v.x; dst[1] = v.y;
    }
    // LayerNorm(x2) -> s_x
    float xv0 = g_x2[(size_t)b * PROJ + t];
    float xv1 = (t < 32) ? g_x2[(size_t)b * PROJ + 1024 + t] : 0.f;
    {
        float ssum = wsum(xv0 + xv1);
        float ssq = wsum(xv0 * xv0 + xv1 * xv1);
        if (l == 0) { s_red[w] = ssum; s_red[16 + w] = ssq; }
    }
    __syncthreads();
    if (t == 0) {
        float S = 0.f, Q = 0.f;
#pragma unroll
        for (int i = 0; i < 16; ++i) { S += s_red[i]; Q += s_red[16 + i]; }
        float mu = S * (1.0f / PROJ);
        float var = Q * (1.0f / PROJ) - mu * mu;
        s_red[32] = mu; s_red[33] = rsqrtf(var + 1e-3f);
    }
    __syncthreads();
    {
        float mu = s_red[32], rs = s_red[33];
        s_x[t] = lnG[t] * ((xv0 - mu) * rs) + lnB[t];
        if (t < 32) s_x[1024 + t] = lnG[1024 + t] * ((xv1 - mu) * rs) + lnB[1024 + t];
    }
    __syncthreads();

    // write-score + softmax -> s_w1 (ww)
    {
        float accw[HN];
#pragma unroll
        for (int h = 0; h < HN; ++h) accw[h] = 0.f;
        const int ub = w << 6;
#pragma unroll 2
        for (int j = 0; j < 64; ++j) {
            int u = ub + j;
            float val = bf2f(s_mem[l * MEMSTRIDE + u]);
            fma16(accw, val, wW + (size_t)HN * __builtin_amdgcn_readfirstlane(u));
        }
        score_phase<true>(s_score, s_w1, s_c, accw, wW, wb, pe, s_x, w, l);
    }
    // mem update in LDS: lane l = m, wave w = u-span -> h(u)=w
    {
        float wwv = s_w1[l * 17 + w];
        const int ub = w << 6;
#pragma unroll 2
        for (int j = 0; j < 64; ++j) {
            int u = ub + j;
            float old = bf2f(s_mem[l * MEMSTRIDE + u]);
            s_mem[l * MEMSTRIDE + u] = f2bf(old + wwv * (s_x[u] - old));
        }
    }
    __syncthreads();

    // next-layer read-score(s) on UPDATED mem
    float acc1[HN], acc2[HN];
#pragma unroll
    for (int h = 0; h < HN; ++h) { acc1[h] = 0.f; acc2[h] = 0.f; }
    s_score[(t >> 4) * 17 + (t & 15)] = 0.f;
    {
        const int ub = w << 6;
#pragma unroll 2
        for (int j = 0; j < 64; ++j) {
            int u = ub + j;
            float val = bf2f(s_mem[l * MEMSTRIDE + u]);
            int uu = __builtin_amdgcn_readfirstlane(u);
            fma16(acc1, val, rW1 + (size_t)HN * uu);
            if (LAST) fma16(acc2, val, rW2 + (size_t)HN * uu);
        }
    }
    __syncthreads();
    score_phase<false>(s_score, s_w1, s_c, acc1, rW1, rb1, pe, nullptr, w, l);
    if (LAST) {
        s_score[(t >> 4) * 17 + (t & 15)] = 0.f;
        __syncthreads();
        score_phase<false>(s_score, s_w2, s_c, acc2, rW2, rb2, pe, nullptr, w, l);
    }

    // mem writeback (coalesced)
    if (!LAST) {
#pragma unroll 2
        for (int k = 0; k < 16; ++k) {
            int flat = (k * 1024 + t) * 4;
            unsigned int* src = (unsigned int*)&s_mem[(flat >> 10) * MEMSTRIDE + (flat & 1023)];
            uint2 v; v.x = src[0]; v.y = src[1];
            *(uint2*)(gm + flat) = v;
        }
    } else {
        float* mo = memout + (size_t)b * (MM * UDIM);
#pragma unroll 2
        for (int k = 0; k < 16; ++k) {
            int flat = (k * 1024 + t) * 4;
            int base = (flat >> 10) * MEMSTRIDE + (flat & 1023);
            float4 v;
            v.x = bf2f(s_mem[base + 0]); v.y = bf2f(s_mem[base + 1]);
            v.z = bf2f(s_mem[base + 2]); v.w = bf2f(s_mem[base + 3]);
            *(float4*)(mo + flat) = v;
        }
    }
    // att / final reads
    {
        const int u = t, h = t >> 6;
        if (!LAST) {
            float a = 0.f;
#pragma unroll 4
            for (int m = 0; m < MM; ++m) a += s_w1[m * 17 + h] * bf2f(s_mem[m * MEMSTRIDE + u]);
            g_att[(size_t)b * UDIM + u] = a;
        } else {
            float a1 = 0.f, a2 = 0.f;
#pragma unroll 4
            for (int m = 0; m < MM; ++m) {
                float val = bf2f(s_mem[m * MEMSTRIDE + u]);
                a1 += s_w1[m * 17 + h] * val;
                a2 += s_w2[m * 17 + h] * val;
            }
            out_final[(size_t)b * 2048 + u] = a1;
            out_final[(size_t)b * 2048 + 1024 + u] = a2;
        }
    }
}

extern "C" void kernel_launch(void* const* d_in, const int* in_sizes, int n_in,
                              void* d_out, int out_size, void* d_ws, size_t ws_size,
                              hipStream_t stream)
{
    const float* inputs = (const float*)d_in[0];
    const float* state  = (const float*)d_in[1];
    const float* pe     = (const float*)d_in[2];
    const float* lnG    = (const float*)d_in[3];
    const float* lnB    = (const float*)d_in[4];
    const float* readW  = (const float*)d_in[5];
    const float* readb  = (const float*)d_in[6];
    const float* writeW = (const float*)d_in[7];
    const float* writeb = (const float*)d_in[8];
    const float* kernW  = (const float*)d_in[9];
    const float* kernb  = (const float*)d_in[10];
    const float* projW  = (const float*)d_in[11];
    const float* projb  = (const float*)d_in[12];
    const float* r1W    = (const float*)d_in[13];
    const float* r1b    = (const float*)d_in[14];
    const float* r2W    = (const float*)d_in[15];
    const float* r2b    = (const float*)d_in[16];
    float* out = (float*)d_out;

    k_init_read<<<BB, 1024, 0, stream>>>(inputs, state, readW, readb, pe);
    for (int L = 0; L < 4; ++L) {
        k_gemm<true ><<<dim3(32, 4), 256, 0, stream>>>(kernW + (size_t)L * UDIM * UDIM,
                                                       kernb + (size_t)L * UDIM, 1024);
        k_gemm<false><<<dim3(33, 4), 256, 0, stream>>>(projW + (size_t)L * UDIM * PROJ,
                                                       projb + (size_t)L * PROJ, PROJ);
        if (L < 3) {
            k_write_read<false><<<BB, 1024, 0, stream>>>(lnG, lnB,
                writeW + (size_t)L * PROJ * HN, writeb + (size_t)L * HN,
                readW + (size_t)(L + 1) * PROJ * HN, readb + (size_t)(L + 1) * HN,
                readW + (size_t)(L + 1) * PROJ * HN, readb + (size_t)(L + 1) * HN,
                pe, nullptr, nullptr);
        } else {
            k_write_read<true><<<BB, 1024, 0, stream>>>(lnG, lnB,
                writeW + (size_t)3 * PROJ * HN, writeb + (size_t)3 * HN,
                r1W, r1b, r2W, r2b,
                pe, out, out + (size_t)BB * 2048);
        }
    }
}

// Round 10
// 499.852 us; speedup vs baseline: 1.8923x; 1.8923x over previous
//
// DNCCell MI355X — round 2 resubmit #8 (rounds 2-9 never ran: GPU acquisition timeouts).
// MFMA score phases, zero global/scalar loads in inner loops.
//
// Key changes vs round 1 (which was latency-bound: 13% VALUBusy, 6.6% HBM, 87% stall):
//  - score[m,h] = mem@W done with mfma_f32_16x16x32_bf16 (weights pre-converted to
//    bf16 transposed [h][k] in g_swT by k_prep_score; staged to LDS in 512-wide slices)
//  - pos-term (batch-independent) precomputed once into g_posr
//  - GEMM weights pre-transposed+bf16 (g_kT/g_pT) once; GEMM uses 32x32 tiles, 256+ blocks
//  - att / update / xpart loops are pure-LDS with ILP; no smem/flat loads inside loops

#include <hip/hip_runtime.h>
#include <cstdint>
#include <cstddef>

#define BB 256
#define MM 64
#define UDIM 1024
#define HN 16
#define POSN 32
#define PROJ 1056
#define MEMS 1026            // s_mem row stride in shorts (odd*2 -> conflict-free scans)
#define WTS 520              // s_wT row stride in shorts (16B-aligned rows, spread banks)

using f32x4 = __attribute__((ext_vector_type(4))) float;
using s16x8 = __attribute__((ext_vector_type(8))) short;
using u16x8 = __attribute__((ext_vector_type(8))) unsigned short;
using u32x4 = __attribute__((ext_vector_type(4))) unsigned int;

__device__ __align__(16) unsigned short g_mem[(size_t)BB * MM * UDIM];
__device__ __align__(16) unsigned short g_att[BB * UDIM];
__device__ __align__(16) unsigned short g_x1[BB * UDIM];
__device__ __align__(16) float g_x2[BB * PROJ];
__device__ __align__(16) unsigned short g_kT[(size_t)4 * 1024 * 1024];   // [l][n][k] bf16
__device__ __align__(16) unsigned short g_pT[(size_t)4 * 1056 * 1024];   // [l][n][k] bf16
__device__ __align__(16) unsigned short g_swT[10 * HN * PROJ];           // [mat][h][p] bf16
__device__ float g_posr[10 * MM * HN];                                   // [mat][m][h]

__device__ __forceinline__ float bf2f(unsigned short u) {
    unsigned int x = ((unsigned int)u) << 16; float f; __builtin_memcpy(&f, &x, 4); return f;
}
__device__ __forceinline__ unsigned short f2bf(float f) {
    unsigned int x; __builtin_memcpy(&x, &f, 4);
    x += 0x7fffu + ((x >> 16) & 1u);
    return (unsigned short)(x >> 16);
}
__device__ __forceinline__ unsigned int packbf(float a, float b) {
    return (unsigned int)f2bf(a) | ((unsigned int)f2bf(b) << 16);
}
__device__ __forceinline__ float wsum(float v) {
#pragma unroll
    for (int o = 32; o; o >>= 1) v += __shfl_xor(v, o);
    return v;
}
__device__ __forceinline__ float wmax(float v) {
#pragma unroll
    for (int o = 32; o; o >>= 1) v = fmaxf(v, __shfl_xor(v, o));
    return v;
}

// ---------------- prep kernels (run once per launch) ----------------

// transpose+convert kernW/projW -> g_kT/g_pT ([n][k] bf16), 64x64 tiles
__global__ __launch_bounds__(256) void k_prep_gemmw(const float* __restrict__ kW,
                                                    const float* __restrict__ pW) {
    int bid = blockIdx.x;
    const float* W; unsigned short* T; int N, kt, nt;
    if (bid < 1024) {
        int lyr = bid >> 8, tile = bid & 255;
        W = kW + (size_t)lyr * 1024 * 1024; T = g_kT + (size_t)lyr * 1024 * 1024;
        N = 1024; kt = tile >> 4; nt = tile & 15;
    } else {
        int b2 = bid - 1024; int lyr = b2 / 272, tile = b2 % 272;
        W = pW + (size_t)lyr * 1024 * 1056; T = g_pT + (size_t)lyr * 1056 * 1024;
        N = 1056; kt = tile / 17; nt = tile % 17;
    }
    int k0 = kt * 64, n0 = nt * 64;
    __shared__ unsigned short s_t[64 * 72];
    int t = threadIdx.x;
    int rr = t >> 4, c4 = (t & 15) * 4;
#pragma unroll
    for (int i = 0; i < 4; ++i) {
        int row = rr + i * 16;
        if (n0 + c4 < N) {
            float4 v = *(const float4*)&W[(size_t)(k0 + row) * N + n0 + c4];
            s_t[row * 72 + c4 + 0] = f2bf(v.x);
            s_t[row * 72 + c4 + 1] = f2bf(v.y);
            s_t[row * 72 + c4 + 2] = f2bf(v.z);
            s_t[row * 72 + c4 + 3] = f2bf(v.w);
        }
    }
    __syncthreads();
    int nn = t >> 4, kq = (t & 15) * 4;
#pragma unroll
    for (int i = 0; i < 4; ++i) {
        int n = nn + i * 16;
        if (n0 + n < N) {
            unsigned int lo = (unsigned int)s_t[(kq + 0) * 72 + n] |
                              ((unsigned int)s_t[(kq + 1) * 72 + n] << 16);
            unsigned int hi = (unsigned int)s_t[(kq + 2) * 72 + n] |
                              ((unsigned int)s_t[(kq + 3) * 72 + n] << 16);
            uint2 v; v.x = lo; v.y = hi;
            *(uint2*)&T[(size_t)(n0 + n) * 1024 + k0 + kq] = v;
        }
    }
}

// score weights -> g_swT ([h][p] bf16) + pos-terms -> g_posr
__global__ __launch_bounds__(1024) void k_prep_score(const float* __restrict__ rW,
                                                     const float* __restrict__ wW,
                                                     const float* __restrict__ r1,
                                                     const float* __restrict__ r2,
                                                     const float* __restrict__ pe) {
    int bid = blockIdx.x, t = threadIdx.x;
    const float* W = (bid < 4) ? rW + (size_t)bid * PROJ * HN
                   : (bid < 8) ? wW + (size_t)(bid - 4) * PROJ * HN
                   : (bid == 8) ? r1 : r2;
    int h = t & 15;
#pragma unroll 4
    for (int j = 0; j < 17; ++j) {
        int p = (t >> 4) + j * 64;
        if (p < PROJ) g_swT[(size_t)bid * (HN * PROJ) + h * PROJ + p] = f2bf(W[p * HN + h]);
    }
    int m = t >> 4;
    float s = 0.f;
#pragma unroll
    for (int p = 0; p < POSN; ++p) s += pe[m * POSN + p] * W[(UDIM + p) * HN + h];
    g_posr[bid * 1024 + t] = s;
}

// ---------------- score phase (MFMA) ----------------
// score[m,h] = sum_u mem[m,u] W[u,h]  via 16x16x32 bf16 MFMA, 2 slices of K=512.
// wave w: m-tile = w&3, k-chunk = w>>2 (128 k each). Reduce via LDS atomics into
// arena-as-score (stride 17). Then mean/x/pos/bias + softmax over m per h.
template<bool WITHX, bool INPLACE>
__device__ __forceinline__ void score_phase(
    unsigned short* s_mem_, unsigned short* s_arena_, float* s_w1_,
    const float* s_x_, const unsigned short* s_wpos_, float* s_c_,
    int mat, const float* __restrict__ bias, int t, int w, int l)
{
    const unsigned short* gswT = g_swT + (size_t)mat * (HN * PROJ);
    const float* posr = g_posr + mat * 1024;
    unsigned short* wT = s_arena_;
    const int mt = w & 3, kc = w >> 2;
    f32x4 acc = {0.f, 0.f, 0.f, 0.f};
    float xp = 0.f;
#pragma unroll
    for (int s = 0; s < 2; ++s) {
        const int k0 = s << 9;
        __syncthreads();   // previous arena use done
        {   int h = t >> 6, kq = (t & 63) << 3;
            u16x8 v = *(const u16x8*)&gswT[h * PROJ + k0 + kq];
            *(u16x8*)&wT[h * WTS + kq] = v;
        }
        __syncthreads();
#pragma unroll
        for (int j = 0; j < 4; ++j) {
            int kk = (kc << 7) + (j << 5) + ((l >> 4) << 3);
            int m = (mt << 4) + (l & 15);
            const unsigned int* pa = (const unsigned int*)&s_mem_[m * MEMS + k0 + kk];
            union { u32x4 u; s16x8 v; } au;
            au.u[0] = pa[0]; au.u[1] = pa[1]; au.u[2] = pa[2]; au.u[3] = pa[3];
            s16x8 bf = *(const s16x8*)&wT[(l & 15) * WTS + kk];
            acc = __builtin_amdgcn_mfma_f32_16x16x32_bf16(au.v, bf, acc, 0, 0, 0);
        }
        if (WITHX) {
#pragma unroll
            for (int i = 0; i < 8; ++i) {
                int p = l + (i << 6);
                xp += s_x_[k0 + p] * bf2f(wT[w * WTS + p]);
            }
        }
    }
    if (WITHX && l < 32) xp += s_x_[1024 + l] * bf2f(s_wpos_[w * 33 + l]);
    __syncthreads();
    float* sc = (float*)s_arena_;          // overlays wT (done with it)
    sc[t] = 0.f;
    if (t < 64) sc[1024 + t] = 0.f;
    __syncthreads();
#pragma unroll
    for (int j = 0; j < 4; ++j)
        atomicAdd(&sc[((mt << 4) + ((l >> 4) << 2) + j) * 17 + (l & 15)], acc[j]);
    __syncthreads();
    {
        float msum = wsum(sc[l * 17 + w]);          // Sum_m mem-part -> mean-key term
        float xps = 0.f;
        if (WITHX) xps = wsum(xp);
        if (l == 0) s_c_[w] = msum * (1.0f / 64.0f) + xps + bias[w];
    }
    __syncthreads();
    {
        float v = sc[l * 17 + w] + s_c_[w] + posr[l * 16 + w];
        float mx = wmax(v);
        float e = __expf(v - mx);
        float sm = wsum(e);
        float r = e / sm;
        if (INPLACE) sc[l * 17 + w] = r;
        else s_w1_[l * 16 + (w ^ (l & 15))] = r;
    }
    __syncthreads();
}

// ---------------- main per-b kernels ----------------

__global__ __launch_bounds__(1024) void k_init(const float* __restrict__ inp,
                                               const float* __restrict__ st,
                                               const float* __restrict__ rb) {
    __shared__ __align__(16) unsigned short s_mem[64 * MEMS];
    __shared__ __align__(16) unsigned short s_arena[HN * WTS];
    __shared__ float s_w1[1024];
    __shared__ float s_c[16];
    const int t = threadIdx.x, b = blockIdx.x, w = t >> 6, l = t & 63;
    const size_t gb = (size_t)b << 16;
#pragma unroll 2
    for (int k = 0; k < 8; ++k) {
        int q = t + (k << 10); int m = q >> 7; int uc = (q & 127) << 3;
        const float4* pi = (const float4*)&inp[gb + (m << 10) + uc];
        const float4* ps = (const float4*)&st[gb + (m << 10) + uc];
        float4 a0 = pi[0], a1 = pi[1], c0 = ps[0], c1 = ps[1];
        unsigned int v0 = packbf(a0.x + c0.x, a0.y + c0.y);
        unsigned int v1 = packbf(a0.z + c0.z, a0.w + c0.w);
        unsigned int v2 = packbf(a1.x + c1.x, a1.y + c1.y);
        unsigned int v3 = packbf(a1.z + c1.z, a1.w + c1.w);
        unsigned int* pl = (unsigned int*)&s_mem[m * MEMS + uc];
        pl[0] = v0; pl[1] = v1; pl[2] = v2; pl[3] = v3;
        u32x4 gv = {v0, v1, v2, v3};
        *(u32x4*)&g_mem[gb + (m << 10) + uc] = gv;
    }
    score_phase<false, false>(s_mem, s_arena, s_w1, nullptr, nullptr, s_c, 0, rb, t, w, l);
    float p0 = 0.f, p1 = 0.f, p2 = 0.f, p3 = 0.f;
#pragma unroll 4
    for (int m = 0; m < 64; m += 4) {
        p0 += s_w1[(m + 0) * 16 + (w ^ ((m + 0) & 15))] * bf2f(s_mem[(m + 0) * MEMS + t]);
        p1 += s_w1[(m + 1) * 16 + (w ^ ((m + 1) & 15))] * bf2f(s_mem[(m + 1) * MEMS + t]);
        p2 += s_w1[(m + 2) * 16 + (w ^ ((m + 2) & 15))] * bf2f(s_mem[(m + 2) * MEMS + t]);
        p3 += s_w1[(m + 3) * 16 + (w ^ ((m + 3) & 15))] * bf2f(s_mem[(m + 3) * MEMS + t]);
    }
    g_att[(b << 10) + t] = f2bf((p0 + p1) + (p2 + p3));
}

template<bool LAST>
__global__ __launch_bounds__(1024) void k_wr(
    const float* __restrict__ lnG, const float* __restrict__ lnB,
    const float* __restrict__ wb_, const float* __restrict__ rb1,
    const float* __restrict__ rb2, int matW, int matR1, int matR2,
    float* __restrict__ out)
{
    __shared__ __align__(16) unsigned short s_mem[64 * MEMS];
    __shared__ __align__(16) unsigned short s_arena[HN * WTS];
    __shared__ float s_w1[1024];
    __shared__ float s_x[PROJ];
    __shared__ unsigned short s_wpos[HN * 33];
    __shared__ float s_c[16];
    __shared__ float s_red[34];
    const int t = threadIdx.x, b = blockIdx.x, w = t >> 6, l = t & 63;
    const size_t gb = (size_t)b << 16;
    // stage mem bf16
#pragma unroll 2
    for (int k = 0; k < 8; ++k) {
        int q = t + (k << 10); int m = q >> 7; int uc = (q & 127) << 3;
        u32x4 v = *(const u32x4*)&g_mem[gb + (m << 10) + uc];
        unsigned int* pl = (unsigned int*)&s_mem[m * MEMS + uc];
        pl[0] = v[0]; pl[1] = v[1]; pl[2] = v[2]; pl[3] = v[3];
    }
    // LayerNorm(x2) -> s_x
    float xv0 = g_x2[(size_t)b * PROJ + t];
    float xv1 = (t < 32) ? g_x2[(size_t)b * PROJ + 1024 + t] : 0.f;
    {
        float ssum = wsum(xv0 + xv1);
        float ssq = wsum(xv0 * xv0 + xv1 * xv1);
        if (l == 0) { s_red[w] = ssum; s_red[16 + w] = ssq; }
    }
    __syncthreads();
    if (t == 0) {
        float S = 0.f, Q = 0.f;
#pragma unroll
        for (int i = 0; i < 16; ++i) { S += s_red[i]; Q += s_red[16 + i]; }
        float mu = S * (1.0f / PROJ);
        float var = Q * (1.0f / PROJ) - mu * mu;
        s_red[32] = mu; s_red[33] = rsqrtf(var + 1e-3f);
    }
    __syncthreads();
    {
        float mu = s_red[32], rs = s_red[33];
        s_x[t] = lnG[t] * ((xv0 - mu) * rs) + lnB[t];
        if (t < 32) s_x[1024 + t] = lnG[1024 + t] * ((xv1 - mu) * rs) + lnB[1024 + t];
        if (t < 512) {
            int hh = t >> 5, pp = t & 31;
            s_wpos[hh * 33 + pp] = g_swT[(size_t)matW * (HN * PROJ) + hh * PROJ + 1024 + pp];
        }
    }
    // write-score + softmax -> s_w1   (score_phase's first barrier covers s_x/s_wpos)
    score_phase<true, false>(s_mem, s_arena, s_w1, s_x, s_wpos, s_c, matW, wb_, t, w, l);
    // mem update: thread t -> column u=t, loop slots m (LDS only, h = w uniform)
    {
        float xu = s_x[t];
#pragma unroll 4
        for (int m = 0; m < 64; ++m) {
            float ww = s_w1[m * 16 + (w ^ (m & 15))];
            int idx = m * MEMS + t;
            float old = bf2f(s_mem[idx]);
            s_mem[idx] = f2bf(old + ww * (xu - old));
        }
    }
    __syncthreads();
    // next read-score(s) on updated mem
    score_phase<false, false>(s_mem, s_arena, s_w1, nullptr, nullptr, s_c, matR1, rb1, t, w, l);
    if (LAST)
        score_phase<false, true>(s_mem, s_arena, s_w1, nullptr, nullptr, s_c, matR2, rb2, t, w, l);
    if (!LAST) {
        float p0 = 0.f, p1 = 0.f, p2 = 0.f, p3 = 0.f;
#pragma unroll 4
        for (int m = 0; m < 64; m += 4) {
            p0 += s_w1[(m + 0) * 16 + (w ^ ((m + 0) & 15))] * bf2f(s_mem[(m + 0) * MEMS + t]);
            p1 += s_w1[(m + 1) * 16 + (w ^ ((m + 1) & 15))] * bf2f(s_mem[(m + 1) * MEMS + t]);
            p2 += s_w1[(m + 2) * 16 + (w ^ ((m + 2) & 15))] * bf2f(s_mem[(m + 2) * MEMS + t]);
            p3 += s_w1[(m + 3) * 16 + (w ^ ((m + 3) & 15))] * bf2f(s_mem[(m + 3) * MEMS + t]);
        }
        g_att[(b << 10) + t] = f2bf((p0 + p1) + (p2 + p3));
#pragma unroll 2
        for (int k = 0; k < 8; ++k) {
            int q = t + (k << 10); int m = q >> 7; int uc = (q & 127) << 3;
            const unsigned int* pl = (const unsigned int*)&s_mem[m * MEMS + uc];
            u32x4 v = {pl[0], pl[1], pl[2], pl[3]};
            *(u32x4*)&g_mem[gb + (m << 10) + uc] = v;
        }
    } else {
        const float* scp = (const float*)s_arena;
        float a1v = 0.f, a2v = 0.f;
#pragma unroll 4
        for (int m = 0; m < 64; ++m) {
            float val = bf2f(s_mem[m * MEMS + t]);
            a1v += s_w1[m * 16 + (w ^ (m & 15))] * val;
            a2v += scp[m * 17 + w] * val;
        }
        out[(size_t)b * 2048 + t] = a1v;
        out[(size_t)b * 2048 + 1024 + t] = a2v;
        float* mo = out + (size_t)BB * 2048 + ((size_t)b << 16);
#pragma unroll 2
        for (int k = 0; k < 16; ++k) {
            int q = t + (k << 10); int m = q >> 8; int uc = (q & 255) << 2;
            const unsigned int* p = (const unsigned int*)&s_mem[m * MEMS + uc];
            unsigned int w0 = p[0], w1v = p[1];
            float4 v;
            v.x = bf2f((unsigned short)(w0 & 0xffff)); v.y = bf2f((unsigned short)(w0 >> 16));
            v.z = bf2f((unsigned short)(w1v & 0xffff)); v.w = bf2f((unsigned short)(w1v >> 16));
            *(float4*)&mo[(m << 10) + uc] = v;
        }
    }
}

// ---------------- batched GEMM: C[256 x N] = op(A @ W + b), A,W bf16 ----------------
template<bool RELU>
__global__ __launch_bounds__(256) void k_gemm(int layer, const float* __restrict__ bias) {
    __shared__ __align__(16) unsigned short s_a[32 * 72];
    __shared__ __align__(16) unsigned short s_b[32 * 72];
    const unsigned short* A = RELU ? g_att : g_x1;
    const unsigned short* T = RELU ? g_kT + (size_t)layer * 1024 * 1024
                                   : g_pT + (size_t)layer * 1056 * 1024;
    const int t = threadIdx.x, w = t >> 6, l = t & 63;
    const int n0 = blockIdx.x << 5, r0 = blockIdx.y << 5;
    const int mh = (w & 1) << 4, nh = (w >> 1) << 4;
    const int ar = t >> 3, kq = (t & 7) << 3;
    f32x4 acc = {0.f, 0.f, 0.f, 0.f};
    for (int k0 = 0; k0 < 1024; k0 += 64) {
        u16x8 va = *(const u16x8*)&A[(size_t)(r0 + ar) * 1024 + k0 + kq];
        u16x8 vb = *(const u16x8*)&T[(size_t)(n0 + ar) * 1024 + k0 + kq];
        __syncthreads();
        *(u16x8*)&s_a[ar * 72 + kq] = va;
        *(u16x8*)&s_b[ar * 72 + kq] = vb;
        __syncthreads();
#pragma unroll
        for (int j = 0; j < 2; ++j) {
            int ko = (j << 5) + ((l >> 4) << 3);
            s16x8 af = *(const s16x8*)&s_a[(mh + (l & 15)) * 72 + ko];
            s16x8 bf = *(const s16x8*)&s_b[(nh + (l & 15)) * 72 + ko];
            acc = __builtin_amdgcn_mfma_f32_16x16x32_bf16(af, bf, acc, 0, 0, 0);
        }
    }
    const int c = n0 + nh + (l & 15);
    const int r = r0 + mh + ((l >> 4) << 2);
    float bv = bias[c];
#pragma unroll
    for (int j = 0; j < 4; ++j) {
        float v = acc[j] + bv;
        if (RELU) { v = fmaxf(v, 0.f); g_x1[(size_t)(r + j) * 1024 + c] = f2bf(v); }
        else      { g_x2[(size_t)(r + j) * 1056 + c] = v; }
    }
}

extern "C" void kernel_launch(void* const* d_in, const int* in_sizes, int n_in,
                              void* d_out, int out_size, void* d_ws, size_t ws_size,
                              hipStream_t stream)
{
    const float* inputs = (const float*)d_in[0];
    const float* state  = (const float*)d_in[1];
    const float* pe     = (const float*)d_in[2];
    const float* lnG    = (const float*)d_in[3];
    const float* lnB    = (const float*)d_in[4];
    const float* readW  = (const float*)d_in[5];
    const float* readb  = (const float*)d_in[6];
    const float* writeW = (const float*)d_in[7];
    const float* writeb = (const float*)d_in[8];
    const float* kernW  = (const float*)d_in[9];
    const float* kernb  = (const float*)d_in[10];
    const float* projW  = (const float*)d_in[11];
    const float* projb  = (const float*)d_in[12];
    const float* r1W    = (const float*)d_in[13];
    const float* r1b    = (const float*)d_in[14];
    const float* r2W    = (const float*)d_in[15];
    const float* r2b    = (const float*)d_in[16];
    float* out = (float*)d_out;

    k_prep_gemmw<<<2112, 256, 0, stream>>>(kernW, projW);
    k_prep_score<<<10, 1024, 0, stream>>>(readW, writeW, r1W, r2W, pe);
    k_init<<<BB, 1024, 0, stream>>>(inputs, state, readb);
    for (int L = 0; L < 4; ++L) {
        k_gemm<true ><<<dim3(32, 8), 256, 0, stream>>>(L, kernb + (size_t)L * 1024);
        k_gemm<false><<<dim3(33, 8), 256, 0, stream>>>(L, projb + (size_t)L * 1056);
        if (L < 3) {
            k_wr<false><<<BB, 1024, 0, stream>>>(lnG, lnB, writeb + L * 16,
                readb + (L + 1) * 16, r1b, 4 + L, L + 1, 0, nullptr);
        } else {
            k_wr<true><<<BB, 1024, 0, stream>>>(lnG, lnB, writeb + 3 * 16,
                r1b, r2b, 7, 8, 9, out);
        }
    }
}